// Round 11
// baseline (4513.619 us; speedup 1.0000x reference)
//
#include <hip/hip_runtime.h>
#include <cstdint>
#include <cstddef>

#define B 128
#define T 64
#define IDIM 128
#define E 256
#define H 512
#define NT 512

#define AT_STRIDE 34
#define AT_CH (128 * AT_STRIDE)   // 4352 floats per 128-k chunk

// LDS pool offsets (floats)
#define OFF_W   0                       // Wlds[640][32] = 20480
#define OFF_A   20480                   // At4[4][AT_CH] = 17408
#define OFF_HC  (OFF_A + 4 * AT_CH)     // hc[1024]
#define OFF_Z1  (OFF_HC + 1024)        // z1s[64]
#define OFF_RED (OFF_Z1 + 64)          // red[128]
#define OFF_BI  (OFF_RED + 128)        // bias[32]
#define POOL_F  (OFF_BI + 32)          // 39136 floats = 156544 B (<160K)

__device__ __forceinline__ float waveReduceSum(float v) {
    for (int off = 32; off > 0; off >>= 1) v += __shfl_xor(v, off, 64);
    return v;
}

__device__ __forceinline__ float fast_tanh(float v) {
    float a = fabsf(v);
    float e = __expf(-2.f * a);
    float r = (1.f - e) * __builtin_amdgcn_rcpf(1.f + e);
    return copysignf(r, v);
}

__device__ __forceinline__ float sigmoidf_(float x) {
    return 1.0f / (1.0f + __expf(-x));
}

// Coherent scalar accessors (bypass stale L1/L2; served at coherence point).
__device__ __forceinline__ float aload(const float* p) {
    return __hip_atomic_load(p, __ATOMIC_RELAXED, __HIP_MEMORY_SCOPE_AGENT);
}
__device__ __forceinline__ void astore(float* p, float v) {
    __hip_atomic_store(p, v, __ATOMIC_RELAXED, __HIP_MEMORY_SCOPE_AGENT);
}

// Coherent 16B load (async — must waitvm0() before using the result).
__device__ __forceinline__ float4 cload4(const float* p) {
    float4 v;
    asm volatile("global_load_dwordx4 %0, %1, off sc0 sc1" : "=v"(v) : "v"(p));
    return v;
}
__device__ __forceinline__ void waitvm0() {
    asm volatile("s_waitcnt vmcnt(0)" ::: "memory");
}

// ---------------------------------------------------------------------------
__global__ __launch_bounds__(256) void news_kernel(
    const float* __restrict__ in, const float* __restrict__ nW,
    const float* __restrict__ nb, float* __restrict__ x)
{
    int out_idx = blockIdx.x * 4 + (threadIdx.x >> 6);
    int lane = threadIdx.x & 63;
    const float4* src = (const float4*)(in + (size_t)out_idx * E);
    float4 a = src[lane];
    float4 wv = ((const float4*)nW)[lane];
    float s = a.x * wv.x + a.y * wv.y + a.z * wv.z + a.w * wv.w;
    s = waveReduceSum(s);
    if (lane == 0) x[out_idx] = s + nb[0];
}

// ---------------------------------------------------------------------------
__global__ __launch_bounds__(64) void z2_kernel(
    const float* __restrict__ x, const float* __restrict__ A2,
    const float* __restrict__ b2, float* __restrict__ z2)
{
    int b = blockIdx.x >> 7;
    int i = blockIdx.x & 127;
    int s = threadIdx.x;
    __shared__ float xs[T];
    xs[s] = x[((size_t)b * T + s) * IDIM + i];
    __syncthreads();
    float acc = b2[s];
    const float* arow = A2 + s * T;
#pragma unroll 8
    for (int tt = 0; tt < T; ++tt) acc += xs[tt] * arow[tt];
    z2[((size_t)b * IDIM + i) * T + s] = acc;
}

// ---------------------------------------------------------------------------
// Per-quarter two-level barrier: 64 blocks = 8 groups x 8. Hot-poll.
__device__ __forceinline__ void qsync(int* cnt, int q, int ns, int ph) {
    __syncthreads();
    if (threadIdx.x == 0) {
        asm volatile("s_waitcnt vmcnt(0) lgkmcnt(0)" ::: "memory");
        int* subp  = cnt + (q * 8 + (ns >> 3)) * 32;
        int* rootp = cnt + 1024 + q * 32;
        int old = __hip_atomic_fetch_add(subp, 1, __ATOMIC_RELAXED,
                                         __HIP_MEMORY_SCOPE_AGENT);
        if (old == ph * 8 - 1)
            __hip_atomic_fetch_add(rootp, 1, __ATOMIC_RELAXED,
                                   __HIP_MEMORY_SCOPE_AGENT);
        int spins = 0;
        while (__hip_atomic_load(rootp, __ATOMIC_RELAXED,
                                 __HIP_MEMORY_SCOPE_AGENT) < ph * 8) {
            if (++spins > (1 << 16)) break;  // fail visibly, never hang
        }
    }
    __syncthreads();
}

// ---------------------------------------------------------------------------
// Persistent scan (verified R5 structure; 2 qsync/step; no register
// preloads — the allocator caps this kernel at 128 VGPRs and spills
// long-lived arrays to scratch/HBM (R9/R10 post-mortem), so all
// t-invariant operands stream from L2/L3 instead).
// Single delta vs R5: after qsync#1, issue w cloads, run the last 16
// k-rows of B1 to hide their latency, then barrier before staging w
// (race-fixed protocol verified in R9).
__global__ __launch_bounds__(NT, 1) void scan_kernel(
    const float* __restrict__ x, const float* __restrict__ z2,
    const float* __restrict__ A1, const float* __restrict__ b1,
    const float* __restrict__ a3w,
    const float* __restrict__ Wih, const float* __restrict__ Whh,
    const float* __restrict__ bih, const float* __restrict__ bhh,
    float* __restrict__ wbuf, float* __restrict__ hbuf, float* __restrict__ cbuf,
    int* __restrict__ cnt, float* __restrict__ out)
{
    __shared__ float pool[POOL_F];
    float* Wlds = pool + OFF_W;
    float* At4  = pool + OFF_A;
    float* hcs  = pool + OFF_HC;
    float* z1s  = pool + OFF_Z1;
    float* redl = pool + OFF_RED;
    float* blds = pool + OFF_BI;

    const int tid  = threadIdx.x;
    const int bid  = blockIdx.x;
    const int lane = tid & 63, wave = tid >> 6;
    const int q = bid >> 6, ns = bid & 63;
    const int b0 = q * 32, n0 = ns * 8;
    const int ab = b0 + (ns >> 1);             // attn batch (pair-shared)
    const int par = ns & 1;                    // which wbuf half to write
    const int jg = lane & 7, bg = lane >> 3;   // compute tile coords
    const int half = tid >> 8;                 // h-staging: 2 halves x 2 chunks
    const int sbh = (tid & 255) >> 3;          // batch row 0..31
    const int st8 = tid & 7;

    // one-time: weight slice (cols j = g*512 + n0 + nn; 4 gates x 8 n)
    for (int idx = tid; idx < 640 * 32; idx += NT) {
        int jj = idx / 640, k = idx - jj * 640;
        int j = (jj >> 3) * 512 + n0 + (jj & 7);
        Wlds[k * 32 + jj] = (k < 128) ? Wih[(size_t)j * 128 + k]
                                      : Whh[(size_t)j * 512 + (k - 128)];
    }
    if (tid < 32) {
        int j = (tid >> 3) * 512 + n0 + (tid & 7);
        blds[tid] = bih[j] + bhh[j];
    }

    // block-local cell state: thread tid<256 owns c[b0 + (tid>>3)][n0 + (tid&7)]
    float cown = 0.f;

    float acc[4][4];   // [ji (j within group)][eb (b within group)]
#define FMA16_(WV0, WV1, WV2, WV3, AV)                                    \
    {                                                                     \
        const float wj_[4] = {WV0, WV1, WV2, WV3};                        \
        const float av_[4] = {AV[0], AV[1], AV[2], AV[3]};                \
        _Pragma("unroll") for (int a_ = 0; a_ < 4; ++a_)                  \
            _Pragma("unroll") for (int b_ = 0; b_ < 4; ++b_)              \
                acc[a_][b_] += wj_[a_] * av_[b_];                         \
    }

    // B1 k-range helper: wave owns kk [wave*64, wave*64+64) of the 512 h-k's
    auto b1run = [&](int i0, int i1) {
        const float* Ab = At4 + (wave >> 1) * AT_CH
                        + ((wave & 1) * 64) * AT_STRIDE + bg * 4;
        const float* Wb = Wlds + (size_t)(128 + wave * 64) * 32 + jg * 4;
        for (int i = i0; i < i1; ++i) {
            float4 wv = *(const float4*)(Wb + (size_t)i * 32);
            float2 a01 = *(const float2*)(Ab + i * AT_STRIDE);
            float2 a23 = *(const float2*)(Ab + i * AT_STRIDE + 2);
            float av[4] = {a01.x, a01.y, a23.x, a23.y};
            FMA16_(wv.x, wv.y, wv.z, wv.w, av);
        }
    };

    int ph = 0;
    for (int t = 0; t < T; ++t) {
        // -------- issue coherent h-panel prefetch (latency hides under attn)
        float4 hv[8];
        {
            const float* hrow = hbuf + (size_t)(b0 + sbh) * H + half * 256;
#pragma unroll
            for (int cc = 0; cc < 2; ++cc)
#pragma unroll
                for (int qq = 0; qq < 4; ++qq)
                    hv[cc * 4 + qq] = cload4(hrow + cc * 128 + (st8 + 8 * qq) * 4);
        }

        // -------- phase A: attention (ALL blocks; pair-duplicated) ----------
        {
            hcs[tid]     = aload(hbuf + (size_t)ab * H + tid);
            hcs[H + tid] = aload(cbuf + (size_t)ab * H + tid);
            __syncthreads();
            // z1: scalar stride-64 LDS reads (2-way, conflict-free)
            for (int r = 0; r < 8; ++r) {
                int tt = r * 8 + wave;
                const float* row = A1 + (size_t)tt * (2 * H);
                float p = 0.f;
#pragma unroll
                for (int qq = 0; qq < 16; ++qq)
                    p += row[lane + qq * 64] * hcs[lane + qq * 64];
                p = waveReduceSum(p);
                if (lane == 0) z1s[tt] = p + b1[tt];
            }
            __syncthreads();
            int i = tid >> 2, qt = tid & 3;
            const float* z2r = z2 + ((size_t)ab * IDIM + i) * T + qt * 16;
            const float* z1p = z1s + qt * 16;
            const float* a3p = a3w + qt * 16;
            float accz = 0.f;
#pragma unroll
            for (int qq = 0; qq < 4; ++qq) {
                float4 zv  = *(const float4*)(z2r + qq * 4);
                float4 z1v = *(const float4*)(z1p + qq * 4);
                float4 a3v = *(const float4*)(a3p + qq * 4);
                accz += fast_tanh(z1v.x + zv.x) * a3v.x
                      + fast_tanh(z1v.y + zv.y) * a3v.y
                      + fast_tanh(z1v.z + zv.z) * a3v.z
                      + fast_tanh(z1v.w + zv.w) * a3v.w;
            }
            accz += __shfl_xor(accz, 1, 64);
            accz += __shfl_xor(accz, 2, 64);
            if (qt == 0) redl[i] = accz;
            __syncthreads();
            if (wave == 0) {
                float v0 = redl[lane], v1 = redl[lane + 64];
                float m = fmaxf(v0, v1);
                for (int off = 32; off > 0; off >>= 1)
                    m = fmaxf(m, __shfl_xor(m, off, 64));
                float e0 = __expf(v0 - m), e1 = __expf(v1 - m);
                float inv = 1.0f / waveReduceSum(e0 + e1);
                const float* xt = x + ((size_t)ab * T + t) * IDIM;
                if (par == 0)
                    astore(wbuf + ab * IDIM + lane,      e0 * inv * xt[lane]);
                else
                    astore(wbuf + ab * IDIM + lane + 64, e1 * inv * xt[lane + 64]);
            }
        }

        // -------- stage h-panel into LDS (transposed, stride-34) ------------
        waitvm0();
        {
#pragma unroll
            for (int cc = 0; cc < 2; ++cc)
#pragma unroll
                for (int qq = 0; qq < 4; ++qq) {
                    float4 v = hv[cc * 4 + qq];
                    float* d = At4 + (half * 2 + cc) * AT_CH
                             + ((st8 + 8 * qq) * 4) * AT_STRIDE + sbh;
                    d[0] = v.x; d[AT_STRIDE] = v.y;
                    d[2 * AT_STRIDE] = v.z; d[3 * AT_STRIDE] = v.w;
                }
        }
        __syncthreads();

        // -------- B1 head: h-part GEMM, wave k-split (48 of 64 kk) ----------
#pragma unroll
        for (int a_ = 0; a_ < 4; ++a_)
#pragma unroll
            for (int b_ = 0; b_ < 4; ++b_) acc[a_][b_] = 0.f;
        b1run(0, 48);

        qsync(cnt, q, ns, ++ph);              // wbuf ready (quarter-local)

        // -------- issue w loads; B1 tail hides their latency ----------------
        float4 w0, w1;
        {
            const float* wrow = wbuf + (size_t)(b0 + (tid >> 4)) * IDIM;
            w0 = cload4(wrow + (tid & 15) * 4);
            w1 = cload4(wrow + ((tid & 15) + 16) * 4);
        }
        b1run(48, 64);
        __syncthreads();                      // ALL At4 reads done (race fix)
        waitvm0();
        {
            int sbw = tid >> 4, st16 = tid & 15;
            float* d0 = At4 + (st16 * 4) * AT_STRIDE + sbw;
            d0[0] = w0.x; d0[AT_STRIDE] = w0.y;
            d0[2 * AT_STRIDE] = w0.z; d0[3 * AT_STRIDE] = w0.w;
            float* d1 = At4 + ((st16 + 16) * 4) * AT_STRIDE + sbw;
            d1[0] = w1.x; d1[AT_STRIDE] = w1.y;
            d1[2 * AT_STRIDE] = w1.z; d1[3 * AT_STRIDE] = w1.w;
        }
        __syncthreads();

        // -------- B2: w-part GEMM (16 kk per wave of 128) -------------------
        {
            const float* Ab = At4 + (wave * 16) * AT_STRIDE + bg * 4;
            const float* Wb = Wlds + (size_t)(wave * 16) * 32 + jg * 4;
#pragma unroll
            for (int i = 0; i < 16; ++i) {
                float4 wv = *(const float4*)(Wb + i * 32);
                float2 a01 = *(const float2*)(Ab + i * AT_STRIDE);
                float2 a23 = *(const float2*)(Ab + i * AT_STRIDE + 2);
                float av[4] = {a01.x, a01.y, a23.x, a23.y};
                FMA16_(wv.x, wv.y, wv.z, wv.w, av);
            }
        }

        // -------- 8-way cross-wave k-reduce (stride-33 + jg-rotation) -------
        float* red4 = At4 + AT_CH;            // chunks 1-2 region (dead)
#pragma unroll
        for (int ji = 0; ji < 4; ++ji) {
            int r = jg * 4 + ji;
#pragma unroll
            for (int eb = 0; eb < 4; ++eb)
                red4[wave * 1056 + r * 33 + bg * 4 + ((eb + jg) & 3)] = acc[ji][eb];
        }
        __syncthreads();

        float* glds = At4;                    // chunk 0 (dead after B2)
        if (tid < 256) {
            int jj = tid >> 3, b8 = tid & 7;
            int rot = jj >> 2;
            float bias = blds[jj];
            float s[4] = {bias, bias, bias, bias};
#pragma unroll
            for (int w = 0; w < 8; ++w) {
                const float* rp = red4 + w * 1056 + jj * 33 + b8 * 4;
#pragma unroll
                for (int eb = 0; eb < 4; ++eb)
                    s[eb] += rp[(eb + rot) & 3];
            }
#pragma unroll
            for (int eb = 0; eb < 4; ++eb)
                glds[jj * 33 + b8 * 4 + eb] = s[eb];
        }
        __syncthreads();
        if (tid < 256) {
            int ub = tid >> 3, un = tid & 7;
            float ig = glds[(0 * 8 + un) * 33 + ub];
            float fg = glds[(1 * 8 + un) * 33 + ub];
            float gg = glds[(2 * 8 + un) * 33 + ub];
            float og = glds[(3 * 8 + un) * 33 + ub];
            int gb = b0 + ub, gn = n0 + un;
            float cnew = sigmoidf_(fg) * cown + sigmoidf_(ig) * tanhf(gg);
            float hnew = sigmoidf_(og) * tanhf(cnew);
            cown = cnew;
            astore(cbuf + (size_t)gb * H + gn, cnew);
            astore(hbuf + (size_t)gb * H + gn, hnew);
            out[((size_t)gb * T + t) * H + gn] = hnew;
        }

        qsync(cnt, q, ns, ++ph);              // h_{t+1}, c_{t+1} ready
    }
}

// ---------------------------------------------------------------------------
extern "C" void kernel_launch(void* const* d_in, const int* in_sizes, int n_in,
                              void* d_out, int out_size, void* d_ws, size_t ws_size,
                              hipStream_t stream)
{
    const float* input  = (const float*)d_in[0];
    const float* news_W = (const float*)d_in[1];
    const float* news_b = (const float*)d_in[2];
    const float* A1     = (const float*)d_in[3];
    const float* b1     = (const float*)d_in[4];
    const float* A2     = (const float*)d_in[5];
    const float* b2     = (const float*)d_in[6];
    const float* a3w    = (const float*)d_in[7];
    // d_in[8] = attn3_b: softmax-invariant, unused
    const float* Wih    = (const float*)d_in[9];
    const float* Whh    = (const float*)d_in[10];
    const float* bih    = (const float*)d_in[11];
    const float* bhh    = (const float*)d_in[12];
    float* out = (float*)d_out;

    char* ws = (char*)d_ws;
    size_t off = 0;
    auto alloc = [&](size_t nelem) {
        float* p = (float*)(ws + off);
        off += ((nelem * 4 + 255) / 256) * 256;
        return p;
    };
    float* x    = alloc((size_t)B * T * IDIM);   // 4 MB
    float* z2   = alloc((size_t)B * IDIM * T);   // 4 MB
    float* wbuf = alloc((size_t)B * IDIM);       // 64 KB
    float* hbuf = alloc((size_t)B * H);          // single h buffer
    float* cbuf = alloc((size_t)B * H);          // single c buffer
    int*   cnt  = (int*)alloc(2048);             // barrier counters

    hipMemsetAsync(hbuf, 0, (size_t)B * H * 4, stream);
    hipMemsetAsync(cbuf, 0, (size_t)B * H * 4, stream);
    hipMemsetAsync(cnt, 0, 2048 * 4, stream);

    news_kernel<<<B * T * IDIM / 4, 256, 0, stream>>>(input, news_W, news_b, x);
    z2_kernel<<<B * IDIM, 64, 0, stream>>>(x, A2, b2, z2);
    scan_kernel<<<256, NT, 0, stream>>>(x, z2, A1, b1, a3w, Wih, Whh, bih, bhh,
                                        wbuf, hbuf, cbuf, cnt, out);
}

// Round 12
// 1376.158 us; speedup vs baseline: 3.2799x; 3.2799x over previous
//
#include <hip/hip_runtime.h>
#include <cstdint>
#include <cstddef>

#define B 128
#define T 64
#define IDIM 128
#define E 256
#define H 512
#define NT 512

#define AT_STRIDE 34
#define AT_CH (128 * AT_STRIDE)   // 4352 floats per 128-k chunk

// LDS pool offsets (floats)
#define OFF_W   0                       // Wlds[640][32] = 20480
#define OFF_A   20480                   // At4[4][AT_CH] = 17408
#define OFF_HC  (OFF_A + 4 * AT_CH)     // hc[1024]
#define OFF_Z1  (OFF_HC + 1024)        // z1s[64]
#define OFF_RED (OFF_Z1 + 64)          // red[128]
#define OFF_BI  (OFF_RED + 128)        // bias[32]
#define POOL_F  (OFF_BI + 32)          // 39136 floats = 156544 B (<160K)

__device__ __forceinline__ float waveReduceSum(float v) {
    for (int off = 32; off > 0; off >>= 1) v += __shfl_xor(v, off, 64);
    return v;
}

__device__ __forceinline__ float fast_tanh(float v) {
    float a = fabsf(v);
    float e = __expf(-2.f * a);
    float r = (1.f - e) * __builtin_amdgcn_rcpf(1.f + e);
    return copysignf(r, v);
}

__device__ __forceinline__ float sigmoidf_(float x) {
    return 1.0f / (1.0f + __expf(-x));
}

// Coherent scalar accessors (bypass stale L1/L2; served at coherence point).
__device__ __forceinline__ float aload(const float* p) {
    return __hip_atomic_load(p, __ATOMIC_RELAXED, __HIP_MEMORY_SCOPE_AGENT);
}
__device__ __forceinline__ void astore(float* p, float v) {
    __hip_atomic_store(p, v, __ATOMIC_RELAXED, __HIP_MEMORY_SCOPE_AGENT);
}

// Coherent 16B load (async — must waitvm0() before using the result).
__device__ __forceinline__ float4 cload4(const float* p) {
    float4 v;
    asm volatile("global_load_dwordx4 %0, %1, off sc0 sc1" : "=v"(v) : "v"(p));
    return v;
}
__device__ __forceinline__ void waitvm0() {
    asm volatile("s_waitcnt vmcnt(0)" ::: "memory");
}

// ---------------------------------------------------------------------------
__global__ __launch_bounds__(256) void news_kernel(
    const float* __restrict__ in, const float* __restrict__ nW,
    const float* __restrict__ nb, float* __restrict__ x)
{
    int out_idx = blockIdx.x * 4 + (threadIdx.x >> 6);
    int lane = threadIdx.x & 63;
    const float4* src = (const float4*)(in + (size_t)out_idx * E);
    float4 a = src[lane];
    float4 wv = ((const float4*)nW)[lane];
    float s = a.x * wv.x + a.y * wv.y + a.z * wv.z + a.w * wv.w;
    s = waveReduceSum(s);
    if (lane == 0) x[out_idx] = s + nb[0];
}

// ---------------------------------------------------------------------------
__global__ __launch_bounds__(64) void z2_kernel(
    const float* __restrict__ x, const float* __restrict__ A2,
    const float* __restrict__ b2, float* __restrict__ z2)
{
    int b = blockIdx.x >> 7;
    int i = blockIdx.x & 127;
    int s = threadIdx.x;
    __shared__ float xs[T];
    xs[s] = x[((size_t)b * T + s) * IDIM + i];
    __syncthreads();
    float acc = b2[s];
    const float* arow = A2 + s * T;
#pragma unroll 8
    for (int tt = 0; tt < T; ++tt) acc += xs[tt] * arow[tt];
    z2[((size_t)b * IDIM + i) * T + s] = acc;
}

// ---------------------------------------------------------------------------
// Per-quarter two-level barrier: 64 blocks = 8 groups x 8. Hot-poll.
__device__ __forceinline__ void qsync(int* cnt, int q, int ns, int ph) {
    __syncthreads();
    if (threadIdx.x == 0) {
        asm volatile("s_waitcnt vmcnt(0) lgkmcnt(0)" ::: "memory");
        int* subp  = cnt + (q * 8 + (ns >> 3)) * 32;
        int* rootp = cnt + 1024 + q * 32;
        int old = __hip_atomic_fetch_add(subp, 1, __ATOMIC_RELAXED,
                                         __HIP_MEMORY_SCOPE_AGENT);
        if (old == ph * 8 - 1)
            __hip_atomic_fetch_add(rootp, 1, __ATOMIC_RELAXED,
                                   __HIP_MEMORY_SCOPE_AGENT);
        int spins = 0;
        while (__hip_atomic_load(rootp, __ATOMIC_RELAXED,
                                 __HIP_MEMORY_SCOPE_AGENT) < ph * 8) {
            if (++spins > (1 << 16)) break;  // fail visibly, never hang
        }
    }
    __syncthreads();
}

// ---------------------------------------------------------------------------
// Persistent scan — EXACT verified R5 configuration (scan 1177 µs, VGPR 116,
// FETCH 108 MB). Three rounds (R9/R10/R11) proved this kernel sits at the
// allocator's 128-VGPR cliff: any live-range extension (register preloads,
// w-load/B1-tail overlap) triggers scratch spills with GB-scale HBM traffic.
// Do not extend live ranges across phases in this kernel.
// 256 blocks x 512 threads; block bid = q*64 + ns. Quarter q owns batches
// q*32..+32; block handles n-slice ns (8 cols/gate). Attention: block pair
// (2m,2m+1) both compute batch b0+m (dup), write disjoint wbuf halves.
// c lives in registers (block-local dataflow).
__global__ __launch_bounds__(NT, 1) void scan_kernel(
    const float* __restrict__ x, const float* __restrict__ z2,
    const float* __restrict__ A1, const float* __restrict__ b1,
    const float* __restrict__ a3w,
    const float* __restrict__ Wih, const float* __restrict__ Whh,
    const float* __restrict__ bih, const float* __restrict__ bhh,
    float* __restrict__ wbuf, float* __restrict__ hbuf, float* __restrict__ cbuf,
    int* __restrict__ cnt, float* __restrict__ out)
{
    __shared__ float pool[POOL_F];
    float* Wlds = pool + OFF_W;
    float* At4  = pool + OFF_A;
    float* hcs  = pool + OFF_HC;
    float* z1s  = pool + OFF_Z1;
    float* redl = pool + OFF_RED;
    float* blds = pool + OFF_BI;

    const int tid  = threadIdx.x;
    const int bid  = blockIdx.x;
    const int lane = tid & 63, wave = tid >> 6;
    const int q = bid >> 6, ns = bid & 63;
    const int b0 = q * 32, n0 = ns * 8;
    const int ab = b0 + (ns >> 1);             // attn batch (pair-shared)
    const int par = ns & 1;                    // which wbuf half to write
    const int jg = lane & 7, bg = lane >> 3;   // compute tile coords
    const int half = tid >> 8;                 // h-staging: 2 halves x 2 chunks
    const int sbh = (tid & 255) >> 3;          // batch row 0..31
    const int st8 = tid & 7;

    // one-time: weight slice (cols j = g*512 + n0 + nn; 4 gates x 8 n)
    for (int idx = tid; idx < 640 * 32; idx += NT) {
        int jj = idx / 640, k = idx - jj * 640;
        int j = (jj >> 3) * 512 + n0 + (jj & 7);
        Wlds[k * 32 + jj] = (k < 128) ? Wih[(size_t)j * 128 + k]
                                      : Whh[(size_t)j * 512 + (k - 128)];
    }
    if (tid < 32) {
        int j = (tid >> 3) * 512 + n0 + (tid & 7);
        blds[tid] = bih[j] + bhh[j];
    }

    // block-local cell state: thread tid<256 owns c[b0 + (tid>>3)][n0 + (tid&7)]
    float cown = 0.f;

    int ph = 0;
    for (int t = 0; t < T; ++t) {
        // -------- issue coherent h-tile prefetch (latency hides under attn)
        float4 hv[8];
        {
            const float* hrow = hbuf + (size_t)(b0 + sbh) * H + half * 256;
#pragma unroll
            for (int cc = 0; cc < 2; ++cc)
#pragma unroll
                for (int qq = 0; qq < 4; ++qq)
                    hv[cc * 4 + qq] = cload4(hrow + cc * 128 + (st8 + 8 * qq) * 4);
        }

        // -------- phase A: attention (ALL blocks; pair-duplicated) ----------
        {
            hcs[tid]     = aload(hbuf + (size_t)ab * H + tid);
            hcs[H + tid] = aload(cbuf + (size_t)ab * H + tid);
            __syncthreads();
            // z1: scalar stride-64 LDS reads (2-way, conflict-free)
            for (int r = 0; r < 8; ++r) {
                int tt = r * 8 + wave;
                const float* row = A1 + (size_t)tt * (2 * H);
                float p = 0.f;
#pragma unroll
                for (int qq = 0; qq < 16; ++qq)
                    p += row[lane + qq * 64] * hcs[lane + qq * 64];
                p = waveReduceSum(p);
                if (lane == 0) z1s[tt] = p + b1[tt];
            }
            __syncthreads();
            int i = tid >> 2, qt = tid & 3;
            const float* z2r = z2 + ((size_t)ab * IDIM + i) * T + qt * 16;
            const float* z1p = z1s + qt * 16;
            const float* a3p = a3w + qt * 16;
            float accz = 0.f;
#pragma unroll
            for (int qq = 0; qq < 4; ++qq) {
                float4 zv  = *(const float4*)(z2r + qq * 4);
                float4 z1v = *(const float4*)(z1p + qq * 4);
                float4 a3v = *(const float4*)(a3p + qq * 4);
                accz += fast_tanh(z1v.x + zv.x) * a3v.x
                      + fast_tanh(z1v.y + zv.y) * a3v.y
                      + fast_tanh(z1v.z + zv.z) * a3v.z
                      + fast_tanh(z1v.w + zv.w) * a3v.w;
            }
            accz += __shfl_xor(accz, 1, 64);
            accz += __shfl_xor(accz, 2, 64);
            if (qt == 0) redl[i] = accz;
            __syncthreads();
            if (wave == 0) {
                float v0 = redl[lane], v1 = redl[lane + 64];
                float m = fmaxf(v0, v1);
                for (int off = 32; off > 0; off >>= 1)
                    m = fmaxf(m, __shfl_xor(m, off, 64));
                float e0 = __expf(v0 - m), e1 = __expf(v1 - m);
                float inv = 1.0f / waveReduceSum(e0 + e1);
                const float* xt = x + ((size_t)ab * T + t) * IDIM;
                if (par == 0)
                    astore(wbuf + ab * IDIM + lane,      e0 * inv * xt[lane]);
                else
                    astore(wbuf + ab * IDIM + lane + 64, e1 * inv * xt[lane + 64]);
            }
        }

        // -------- stage h-tile into LDS (transposed, stride-34) -------------
        waitvm0();
        {
#pragma unroll
            for (int cc = 0; cc < 2; ++cc)
#pragma unroll
                for (int qq = 0; qq < 4; ++qq) {
                    float4 v = hv[cc * 4 + qq];
                    float* d = At4 + (half * 2 + cc) * AT_CH
                             + ((st8 + 8 * qq) * 4) * AT_STRIDE + sbh;
                    d[0] = v.x; d[AT_STRIDE] = v.y;
                    d[2 * AT_STRIDE] = v.z; d[3 * AT_STRIDE] = v.w;
                }
        }
        __syncthreads();

        // -------- B1: h-part GEMM, wave k-split (64 kk each of 512) ---------
        float acc[4][4];   // [ji (j within group)][eb (b within group)]
#pragma unroll
        for (int a_ = 0; a_ < 4; ++a_)
#pragma unroll
            for (int b_ = 0; b_ < 4; ++b_) acc[a_][b_] = 0.f;
        {
            const float* Ab = At4 + (wave >> 1) * AT_CH
                            + ((wave & 1) * 64) * AT_STRIDE + bg * 4;
            const float* Wb = Wlds + (size_t)(128 + wave * 64) * 32 + jg * 4;
#pragma unroll 8
            for (int i = 0; i < 64; ++i) {
                float4 wv = *(const float4*)(Wb + i * 32);
                float2 a01 = *(const float2*)(Ab + i * AT_STRIDE);
                float2 a23 = *(const float2*)(Ab + i * AT_STRIDE + 2);
                float av[4] = {a01.x, a01.y, a23.x, a23.y};
                const float wj[4] = {wv.x, wv.y, wv.z, wv.w};
#pragma unroll
                for (int a_ = 0; a_ < 4; ++a_)
#pragma unroll
                    for (int b_ = 0; b_ < 4; ++b_)
                        acc[a_][b_] += wj[a_] * av[b_];
            }
        }

        qsync(cnt, q, ns, ++ph);              // wbuf ready (quarter-local)

        // -------- stage w-tile, B2: w-part GEMM (16 kk each of 128) ---------
        {
            const float* wrow = wbuf + (size_t)(b0 + (tid >> 4)) * IDIM;
            float4 w0 = cload4(wrow + (tid & 15) * 4);
            float4 w1 = cload4(wrow + ((tid & 15) + 16) * 4);
            waitvm0();
            int sbw = tid >> 4, st16 = tid & 15;
            float* d0 = At4 + (st16 * 4) * AT_STRIDE + sbw;
            d0[0] = w0.x; d0[AT_STRIDE] = w0.y;
            d0[2 * AT_STRIDE] = w0.z; d0[3 * AT_STRIDE] = w0.w;
            float* d1 = At4 + ((st16 + 16) * 4) * AT_STRIDE + sbw;
            d1[0] = w1.x; d1[AT_STRIDE] = w1.y;
            d1[2 * AT_STRIDE] = w1.z; d1[3 * AT_STRIDE] = w1.w;
        }
        __syncthreads();
        {
            const float* Ab = At4 + (wave * 16) * AT_STRIDE + bg * 4;
            const float* Wb = Wlds + (size_t)(wave * 16) * 32 + jg * 4;
#pragma unroll
            for (int i = 0; i < 16; ++i) {
                float4 wv = *(const float4*)(Wb + i * 32);
                float2 a01 = *(const float2*)(Ab + i * AT_STRIDE);
                float2 a23 = *(const float2*)(Ab + i * AT_STRIDE + 2);
                float av[4] = {a01.x, a01.y, a23.x, a23.y};
                const float wj[4] = {wv.x, wv.y, wv.z, wv.w};
#pragma unroll
                for (int a_ = 0; a_ < 4; ++a_)
#pragma unroll
                    for (int b_ = 0; b_ < 4; ++b_)
                        acc[a_][b_] += wj[a_] * av[b_];
            }
        }

        // -------- 8-way cross-wave k-reduce (stride-33 + jg-rotation) -------
        float* red4 = At4 + AT_CH;            // 8448 floats, chunks 1-2 (dead)
#pragma unroll
        for (int ji = 0; ji < 4; ++ji) {
            int r = jg * 4 + ji;
#pragma unroll
            for (int eb = 0; eb < 4; ++eb)
                red4[wave * 1056 + r * 33 + bg * 4 + ((eb + jg) & 3)] = acc[ji][eb];
        }
        __syncthreads();

        float* glds = At4;                    // chunk 0 (dead after B2)
        if (tid < 256) {
            int jj = tid >> 3, b8 = tid & 7;
            int rot = jj >> 2;
            float bias = blds[jj];
            float s[4] = {bias, bias, bias, bias};
#pragma unroll
            for (int w = 0; w < 8; ++w) {
                const float* rp = red4 + w * 1056 + jj * 33 + b8 * 4;
#pragma unroll
                for (int eb = 0; eb < 4; ++eb)
                    s[eb] += rp[(eb + rot) & 3];
            }
#pragma unroll
            for (int eb = 0; eb < 4; ++eb)
                glds[jj * 33 + b8 * 4 + eb] = s[eb];
        }
        __syncthreads();
        if (tid < 256) {
            int ub = tid >> 3, un = tid & 7;
            float ig = glds[(0 * 8 + un) * 33 + ub];
            float fg = glds[(1 * 8 + un) * 33 + ub];
            float gg = glds[(2 * 8 + un) * 33 + ub];
            float og = glds[(3 * 8 + un) * 33 + ub];
            int gb = b0 + ub, gn = n0 + un;
            float cnew = sigmoidf_(fg) * cown + sigmoidf_(ig) * tanhf(gg);
            float hnew = sigmoidf_(og) * tanhf(cnew);
            cown = cnew;
            astore(cbuf + (size_t)gb * H + gn, cnew);
            astore(hbuf + (size_t)gb * H + gn, hnew);
            out[((size_t)gb * T + t) * H + gn] = hnew;
        }

        qsync(cnt, q, ns, ++ph);              // h_{t+1}, c_{t+1} ready
    }
}

// ---------------------------------------------------------------------------
extern "C" void kernel_launch(void* const* d_in, const int* in_sizes, int n_in,
                              void* d_out, int out_size, void* d_ws, size_t ws_size,
                              hipStream_t stream)
{
    const float* input  = (const float*)d_in[0];
    const float* news_W = (const float*)d_in[1];
    const float* news_b = (const float*)d_in[2];
    const float* A1     = (const float*)d_in[3];
    const float* b1     = (const float*)d_in[4];
    const float* A2     = (const float*)d_in[5];
    const float* b2     = (const float*)d_in[6];
    const float* a3w    = (const float*)d_in[7];
    // d_in[8] = attn3_b: softmax-invariant, unused
    const float* Wih    = (const float*)d_in[9];
    const float* Whh    = (const float*)d_in[10];
    const float* bih    = (const float*)d_in[11];
    const float* bhh    = (const float*)d_in[12];
    float* out = (float*)d_out;

    char* ws = (char*)d_ws;
    size_t off = 0;
    auto alloc = [&](size_t nelem) {
        float* p = (float*)(ws + off);
        off += ((nelem * 4 + 255) / 256) * 256;
        return p;
    };
    float* x    = alloc((size_t)B * T * IDIM);   // 4 MB
    float* z2   = alloc((size_t)B * IDIM * T);   // 4 MB
    float* wbuf = alloc((size_t)B * IDIM);       // 64 KB
    float* hbuf = alloc((size_t)B * H);          // single h buffer
    float* cbuf = alloc((size_t)B * H);          // single c buffer
    int*   cnt  = (int*)alloc(2048);             // barrier counters

    hipMemsetAsync(hbuf, 0, (size_t)B * H * 4, stream);
    hipMemsetAsync(cbuf, 0, (size_t)B * H * 4, stream);
    hipMemsetAsync(cnt, 0, 2048 * 4, stream);

    news_kernel<<<B * T * IDIM / 4, 256, 0, stream>>>(input, news_W, news_b, x);
    z2_kernel<<<B * IDIM, 64, 0, stream>>>(x, A2, b2, z2);
    scan_kernel<<<256, NT, 0, stream>>>(x, z2, A1, b1, a3w, Wih, Whh, bih, bhh,
                                        wbuf, hbuf, cbuf, cnt, out);
}

// Round 13
// 1245.011 us; speedup vs baseline: 3.6254x; 1.1053x over previous
//
#include <hip/hip_runtime.h>
#include <cstdint>
#include <cstddef>

#define B 128
#define T 64
#define IDIM 128
#define E 256
#define H 512
#define NT 512

#define AT_STRIDE 34
#define AT_CH (128 * AT_STRIDE)   // 4352 floats per 128-k chunk

// LDS pool offsets (floats)
#define OFF_W   0                       // Wlds[640][32] = 20480
#define OFF_A   20480                   // At4[4][AT_CH] = 17408
#define OFF_HC  (OFF_A + 4 * AT_CH)     // hc[1024]
#define OFF_Z1  (OFF_HC + 1024)        // z1s[64]
#define OFF_RED (OFF_Z1 + 64)          // red[128]
#define OFF_BI  (OFF_RED + 128)        // bias[32]
#define POOL_F  (OFF_BI + 32)          // 39136 floats = 156544 B (<160K)

__device__ __forceinline__ float waveReduceSum(float v) {
    for (int off = 32; off > 0; off >>= 1) v += __shfl_xor(v, off, 64);
    return v;
}

__device__ __forceinline__ float fast_tanh(float v) {
    float a = fabsf(v);
    float e = __expf(-2.f * a);
    float r = (1.f - e) * __builtin_amdgcn_rcpf(1.f + e);
    return copysignf(r, v);
}

__device__ __forceinline__ float sigmoidf_(float x) {
    return 1.0f / (1.0f + __expf(-x));
}

// Coherent scalar accessors (bypass stale L1/L2; served at coherence point).
__device__ __forceinline__ float aload(const float* p) {
    return __hip_atomic_load(p, __ATOMIC_RELAXED, __HIP_MEMORY_SCOPE_AGENT);
}
__device__ __forceinline__ void astore(float* p, float v) {
    __hip_atomic_store(p, v, __ATOMIC_RELAXED, __HIP_MEMORY_SCOPE_AGENT);
}

// Coherent 16B load (async — must waitvm0() before using the result).
__device__ __forceinline__ float4 cload4(const float* p) {
    float4 v;
    asm volatile("global_load_dwordx4 %0, %1, off sc0 sc1" : "=v"(v) : "v"(p));
    return v;
}
__device__ __forceinline__ void waitvm0() {
    asm volatile("s_waitcnt vmcnt(0)" ::: "memory");
}

// ---------------------------------------------------------------------------
__global__ __launch_bounds__(256) void news_kernel(
    const float* __restrict__ in, const float* __restrict__ nW,
    const float* __restrict__ nb, float* __restrict__ x)
{
    int out_idx = blockIdx.x * 4 + (threadIdx.x >> 6);
    int lane = threadIdx.x & 63;
    const float4* src = (const float4*)(in + (size_t)out_idx * E);
    float4 a = src[lane];
    float4 wv = ((const float4*)nW)[lane];
    float s = a.x * wv.x + a.y * wv.y + a.z * wv.z + a.w * wv.w;
    s = waveReduceSum(s);
    if (lane == 0) x[out_idx] = s + nb[0];
}

// ---------------------------------------------------------------------------
__global__ __launch_bounds__(64) void z2_kernel(
    const float* __restrict__ x, const float* __restrict__ A2,
    const float* __restrict__ b2, float* __restrict__ z2)
{
    int b = blockIdx.x >> 7;
    int i = blockIdx.x & 127;
    int s = threadIdx.x;
    __shared__ float xs[T];
    xs[s] = x[((size_t)b * T + s) * IDIM + i];
    __syncthreads();
    float acc = b2[s];
    const float* arow = A2 + s * T;
#pragma unroll 8
    for (int tt = 0; tt < T; ++tt) acc += xs[tt] * arow[tt];
    z2[((size_t)b * IDIM + i) * T + s] = acc;
}

// ---------------------------------------------------------------------------
// Split per-quarter two-level barrier: 64 blocks = 8 groups x 8.
// qarrive: publish arrival (stores drained by the syncthreads);
// qwait: poll root until the phase completes. Work placed between the two
// overlaps barrier-tree propagation (~1.5-2 µs) with useful local compute.
// Barrier duty on tid NT-1 (wave 7) — wave 0 is the softmax straggler.
__device__ __forceinline__ void qarrive(int* cnt, int q, int ns, int ph) {
    __syncthreads();                     // all waves drain vmem before arrive
    if (threadIdx.x == NT - 1) {
        asm volatile("s_waitcnt vmcnt(0) lgkmcnt(0)" ::: "memory");
        int* subp  = cnt + (q * 8 + (ns >> 3)) * 32;
        int* rootp = cnt + 1024 + q * 32;
        int old = __hip_atomic_fetch_add(subp, 1, __ATOMIC_RELAXED,
                                         __HIP_MEMORY_SCOPE_AGENT);
        if (old == ph * 8 - 1)
            __hip_atomic_fetch_add(rootp, 1, __ATOMIC_RELAXED,
                                   __HIP_MEMORY_SCOPE_AGENT);
    }
}
__device__ __forceinline__ void qwait(int* cnt, int q, int ph) {
    if (threadIdx.x == NT - 1) {
        int* rootp = cnt + 1024 + q * 32;
        int spins = 0;
        while (__hip_atomic_load(rootp, __ATOMIC_RELAXED,
                                 __HIP_MEMORY_SCOPE_AGENT) < ph * 8) {
            if (++spins > (1 << 16)) break;  // fail visibly, never hang
        }
    }
    __syncthreads();
}

// ---------------------------------------------------------------------------
// Persistent scan — verified R5/R12 structure with SPLIT barriers.
// R9/R10/R11 lesson: this kernel sits at the allocator's 128-VGPR cliff;
// do NOT extend live ranges across phases. This round's change is pure
// reordering: arrive early / wait late, with stage+B1 inside window #1 and
// the out-store (single scalar hnew held) inside window #2.
__global__ __launch_bounds__(NT, 1) void scan_kernel(
    const float* __restrict__ x, const float* __restrict__ z2,
    const float* __restrict__ A1, const float* __restrict__ b1,
    const float* __restrict__ a3w,
    const float* __restrict__ Wih, const float* __restrict__ Whh,
    const float* __restrict__ bih, const float* __restrict__ bhh,
    float* __restrict__ wbuf, float* __restrict__ hbuf, float* __restrict__ cbuf,
    int* __restrict__ cnt, float* __restrict__ out)
{
    __shared__ float pool[POOL_F];
    float* Wlds = pool + OFF_W;
    float* At4  = pool + OFF_A;
    float* hcs  = pool + OFF_HC;
    float* z1s  = pool + OFF_Z1;
    float* redl = pool + OFF_RED;
    float* blds = pool + OFF_BI;

    const int tid  = threadIdx.x;
    const int bid  = blockIdx.x;
    const int lane = tid & 63, wave = tid >> 6;
    const int q = bid >> 6, ns = bid & 63;
    const int b0 = q * 32, n0 = ns * 8;
    const int ab = b0 + (ns >> 1);             // attn batch (pair-shared)
    const int par = ns & 1;                    // which wbuf half to write
    const int jg = lane & 7, bg = lane >> 3;   // compute tile coords
    const int half = tid >> 8;                 // h-staging: 2 halves x 2 chunks
    const int sbh = (tid & 255) >> 3;          // batch row 0..31
    const int st8 = tid & 7;

    // one-time: weight slice (cols j = g*512 + n0 + nn; 4 gates x 8 n)
    for (int idx = tid; idx < 640 * 32; idx += NT) {
        int jj = idx / 640, k = idx - jj * 640;
        int j = (jj >> 3) * 512 + n0 + (jj & 7);
        Wlds[k * 32 + jj] = (k < 128) ? Wih[(size_t)j * 128 + k]
                                      : Whh[(size_t)j * 512 + (k - 128)];
    }
    if (tid < 32) {
        int j = (tid >> 3) * 512 + n0 + (tid & 7);
        blds[tid] = bih[j] + bhh[j];
    }

    // block-local cell state: thread tid<256 owns c[b0 + (tid>>3)][n0 + (tid&7)]
    float cown = 0.f;

    int ph = 0;
    for (int t = 0; t < T; ++t) {
        // -------- issue coherent h-tile prefetch (latency hides under attn)
        float4 hv[8];
        {
            const float* hrow = hbuf + (size_t)(b0 + sbh) * H + half * 256;
#pragma unroll
            for (int cc = 0; cc < 2; ++cc)
#pragma unroll
                for (int qq = 0; qq < 4; ++qq)
                    hv[cc * 4 + qq] = cload4(hrow + cc * 128 + (st8 + 8 * qq) * 4);
        }

        // -------- phase A: attention (ALL blocks; pair-duplicated) ----------
        {
            hcs[tid]     = aload(hbuf + (size_t)ab * H + tid);
            hcs[H + tid] = aload(cbuf + (size_t)ab * H + tid);
            __syncthreads();
            // z1: scalar stride-64 LDS reads (2-way, conflict-free)
            for (int r = 0; r < 8; ++r) {
                int tt = r * 8 + wave;
                const float* row = A1 + (size_t)tt * (2 * H);
                float p = 0.f;
#pragma unroll
                for (int qq = 0; qq < 16; ++qq)
                    p += row[lane + qq * 64] * hcs[lane + qq * 64];
                p = waveReduceSum(p);
                if (lane == 0) z1s[tt] = p + b1[tt];
            }
            __syncthreads();
            int i = tid >> 2, qt = tid & 3;
            const float* z2r = z2 + ((size_t)ab * IDIM + i) * T + qt * 16;
            const float* z1p = z1s + qt * 16;
            const float* a3p = a3w + qt * 16;
            float accz = 0.f;
#pragma unroll
            for (int qq = 0; qq < 4; ++qq) {
                float4 zv  = *(const float4*)(z2r + qq * 4);
                float4 z1v = *(const float4*)(z1p + qq * 4);
                float4 a3v = *(const float4*)(a3p + qq * 4);
                accz += fast_tanh(z1v.x + zv.x) * a3v.x
                      + fast_tanh(z1v.y + zv.y) * a3v.y
                      + fast_tanh(z1v.z + zv.z) * a3v.z
                      + fast_tanh(z1v.w + zv.w) * a3v.w;
            }
            accz += __shfl_xor(accz, 1, 64);
            accz += __shfl_xor(accz, 2, 64);
            if (qt == 0) redl[i] = accz;
            __syncthreads();
            if (wave == 0) {
                float v0 = redl[lane], v1 = redl[lane + 64];
                float m = fmaxf(v0, v1);
                for (int off = 32; off > 0; off >>= 1)
                    m = fmaxf(m, __shfl_xor(m, off, 64));
                float e0 = __expf(v0 - m), e1 = __expf(v1 - m);
                float inv = 1.0f / waveReduceSum(e0 + e1);
                const float* xt = x + ((size_t)ab * T + t) * IDIM;
                if (par == 0)
                    astore(wbuf + ab * IDIM + lane,      e0 * inv * xt[lane]);
                else
                    astore(wbuf + ab * IDIM + lane + 64, e1 * inv * xt[lane + 64]);
            }
        }

        // -------- ARRIVE #1 (wbuf published); tree propagates under B1 ------
        ++ph;
        qarrive(cnt, q, ns, ph);

        // -------- stage h-tile into LDS (transposed, stride-34) -------------
        waitvm0();
        {
#pragma unroll
            for (int cc = 0; cc < 2; ++cc)
#pragma unroll
                for (int qq = 0; qq < 4; ++qq) {
                    float4 v = hv[cc * 4 + qq];
                    float* d = At4 + (half * 2 + cc) * AT_CH
                             + ((st8 + 8 * qq) * 4) * AT_STRIDE + sbh;
                    d[0] = v.x; d[AT_STRIDE] = v.y;
                    d[2 * AT_STRIDE] = v.z; d[3 * AT_STRIDE] = v.w;
                }
        }
        __syncthreads();

        // -------- B1: h-part GEMM, wave k-split (64 kk each of 512) ---------
        float acc[4][4];   // [ji (j within group)][eb (b within group)]
#pragma unroll
        for (int a_ = 0; a_ < 4; ++a_)
#pragma unroll
            for (int b_ = 0; b_ < 4; ++b_) acc[a_][b_] = 0.f;
        {
            const float* Ab = At4 + (wave >> 1) * AT_CH
                            + ((wave & 1) * 64) * AT_STRIDE + bg * 4;
            const float* Wb = Wlds + (size_t)(128 + wave * 64) * 32 + jg * 4;
#pragma unroll 8
            for (int i = 0; i < 64; ++i) {
                float4 wv = *(const float4*)(Wb + i * 32);
                float2 a01 = *(const float2*)(Ab + i * AT_STRIDE);
                float2 a23 = *(const float2*)(Ab + i * AT_STRIDE + 2);
                float av[4] = {a01.x, a01.y, a23.x, a23.y};
                const float wj[4] = {wv.x, wv.y, wv.z, wv.w};
#pragma unroll
                for (int a_ = 0; a_ < 4; ++a_)
#pragma unroll
                    for (int b_ = 0; b_ < 4; ++b_)
                        acc[a_][b_] += wj[a_] * av[b_];
            }
        }

        qwait(cnt, q, ph);                    // wbuf ready (quarter-local)

        // -------- stage w-tile, B2: w-part GEMM (16 kk each of 128) ---------
        {
            const float* wrow = wbuf + (size_t)(b0 + (tid >> 4)) * IDIM;
            float4 w0 = cload4(wrow + (tid & 15) * 4);
            float4 w1 = cload4(wrow + ((tid & 15) + 16) * 4);
            waitvm0();
            int sbw = tid >> 4, st16 = tid & 15;
            float* d0 = At4 + (st16 * 4) * AT_STRIDE + sbw;
            d0[0] = w0.x; d0[AT_STRIDE] = w0.y;
            d0[2 * AT_STRIDE] = w0.z; d0[3 * AT_STRIDE] = w0.w;
            float* d1 = At4 + ((st16 + 16) * 4) * AT_STRIDE + sbw;
            d1[0] = w1.x; d1[AT_STRIDE] = w1.y;
            d1[2 * AT_STRIDE] = w1.z; d1[3 * AT_STRIDE] = w1.w;
        }
        __syncthreads();
        {
            const float* Ab = At4 + (wave * 16) * AT_STRIDE + bg * 4;
            const float* Wb = Wlds + (size_t)(wave * 16) * 32 + jg * 4;
#pragma unroll
            for (int i = 0; i < 16; ++i) {
                float4 wv = *(const float4*)(Wb + i * 32);
                float2 a01 = *(const float2*)(Ab + i * AT_STRIDE);
                float2 a23 = *(const float2*)(Ab + i * AT_STRIDE + 2);
                float av[4] = {a01.x, a01.y, a23.x, a23.y};
                const float wj[4] = {wv.x, wv.y, wv.z, wv.w};
#pragma unroll
                for (int a_ = 0; a_ < 4; ++a_)
#pragma unroll
                    for (int b_ = 0; b_ < 4; ++b_)
                        acc[a_][b_] += wj[a_] * av[b_];
            }
        }

        // -------- 8-way cross-wave k-reduce (stride-33 + jg-rotation) -------
        float* red4 = At4 + AT_CH;            // 8448 floats, chunks 1-2 (dead)
#pragma unroll
        for (int ji = 0; ji < 4; ++ji) {
            int r = jg * 4 + ji;
#pragma unroll
            for (int eb = 0; eb < 4; ++eb)
                red4[wave * 1056 + r * 33 + bg * 4 + ((eb + jg) & 3)] = acc[ji][eb];
        }
        __syncthreads();

        float* glds = At4;                    // chunk 0 (dead after B2)
        if (tid < 256) {
            int jj = tid >> 3, b8 = tid & 7;
            int rot = jj >> 2;
            float bias = blds[jj];
            float s[4] = {bias, bias, bias, bias};
#pragma unroll
            for (int w = 0; w < 8; ++w) {
                const float* rp = red4 + w * 1056 + jj * 33 + b8 * 4;
#pragma unroll
                for (int eb = 0; eb < 4; ++eb)
                    s[eb] += rp[(eb + rot) & 3];
            }
#pragma unroll
            for (int eb = 0; eb < 4; ++eb)
                glds[jj * 33 + b8 * 4 + eb] = s[eb];
        }
        __syncthreads();
        float hnew = 0.f;
        if (tid < 256) {
            int ub = tid >> 3, un = tid & 7;
            float ig = glds[(0 * 8 + un) * 33 + ub];
            float fg = glds[(1 * 8 + un) * 33 + ub];
            float gg = glds[(2 * 8 + un) * 33 + ub];
            float og = glds[(3 * 8 + un) * 33 + ub];
            int gb = b0 + ub, gn = n0 + un;
            float cnew = sigmoidf_(fg) * cown + sigmoidf_(ig) * tanhf(gg);
            hnew = sigmoidf_(og) * tanhf(cnew);
            cown = cnew;
            astore(cbuf + (size_t)gb * H + gn, cnew);
            astore(hbuf + (size_t)gb * H + gn, hnew);
        }

        // -------- ARRIVE #2 (h,c published); out-store under propagation ----
        ++ph;
        qarrive(cnt, q, ns, ph);
        if (tid < 256) {
            int gb = b0 + (tid >> 3), gn = n0 + (tid & 7);
            out[((size_t)gb * T + t) * H + gn] = hnew;
        }
        qwait(cnt, q, ph);                    // h_{t+1}, c_{t+1} ready
    }
}

// ---------------------------------------------------------------------------
extern "C" void kernel_launch(void* const* d_in, const int* in_sizes, int n_in,
                              void* d_out, int out_size, void* d_ws, size_t ws_size,
                              hipStream_t stream)
{
    const float* input  = (const float*)d_in[0];
    const float* news_W = (const float*)d_in[1];
    const float* news_b = (const float*)d_in[2];
    const float* A1     = (const float*)d_in[3];
    const float* b1     = (const float*)d_in[4];
    const float* A2     = (const float*)d_in[5];
    const float* b2     = (const float*)d_in[6];
    const float* a3w    = (const float*)d_in[7];
    // d_in[8] = attn3_b: softmax-invariant, unused
    const float* Wih    = (const float*)d_in[9];
    const float* Whh    = (const float*)d_in[10];
    const float* bih    = (const float*)d_in[11];
    const float* bhh    = (const float*)d_in[12];
    float* out = (float*)d_out;

    char* ws = (char*)d_ws;
    size_t off = 0;
    auto alloc = [&](size_t nelem) {
        float* p = (float*)(ws + off);
        off += ((nelem * 4 + 255) / 256) * 256;
        return p;
    };
    float* x    = alloc((size_t)B * T * IDIM);   // 4 MB
    float* z2   = alloc((size_t)B * IDIM * T);   // 4 MB
    float* wbuf = alloc((size_t)B * IDIM);       // 64 KB
    float* hbuf = alloc((size_t)B * H);          // single h buffer
    float* cbuf = alloc((size_t)B * H);          // single c buffer
    int*   cnt  = (int*)alloc(2048);             // barrier counters

    hipMemsetAsync(hbuf, 0, (size_t)B * H * 4, stream);
    hipMemsetAsync(cbuf, 0, (size_t)B * H * 4, stream);
    hipMemsetAsync(cnt, 0, 2048 * 4, stream);

    news_kernel<<<B * T * IDIM / 4, 256, 0, stream>>>(input, news_W, news_b, x);
    z2_kernel<<<B * IDIM, 64, 0, stream>>>(x, A2, b2, z2);
    scan_kernel<<<256, NT, 0, stream>>>(x, z2, A1, b1, a3w, Wih, Whh, bih, bhh,
                                        wbuf, hbuf, cbuf, cnt, out);
}